// Round 10
// baseline (406.972 us; speedup 1.0000x reference)
//
#include <hip/hip_runtime.h>
#include <hip/hip_bf16.h>

// LSTM decoder: B=2048, L=64, H=128, O=64, T=512.  Output: FLOAT32 [B,T,O].
// Identities:
//   next input x == h  =>  t>=1: gates = h @ (W_ih+W_hh)^T + (b_ih+b_hh)
//   t==0 (x=0):            gates = h0 @ W_hh^T + (b_ih+b_hh)
// r10: cleaned i8-limb MFMA (r7 math, verified absmax 9.77e-4, minus overhead):
//   - mfma_i32_16x16x64_i8: gates = 8 instr/wave (vs 16 bf16)
//   - h rows 2b=hi8, 2b+1=lo8; h = hi8/127 + lo8/16256 (14-bit)
//   - W single-i8 per-column scale; Wo 2-limb i8
//   - NO setprio (r9 proved null); h0 scale-4 folded into step-0 kc (no
//     per-step ascale mul); limb combine acc*128+acc_o (shift-add)
//   - 2 x ds_read_b128 per lane per step (bank-conflict-free, r7: counter=0)

#define H_DIM 128
#define L_DIM 64
#define O_DIM 64
#define ROWS 8
#define THREADS 512
#define LOG2E 1.44269504f

typedef __attribute__((ext_vector_type(4))) float float4v;
typedef __attribute__((ext_vector_type(4))) int i32x4;

__device__ __forceinline__ unsigned swzf(int r) {
  return (unsigned)(((r & 7) << 4) ^ ((r & 8) << 2));
}
__device__ __forceinline__ float fast_exp2(float x) {
#if __has_builtin(__builtin_amdgcn_exp2f)
  return __builtin_amdgcn_exp2f(x);
#else
  return exp2f(x);
#endif
}
__device__ __forceinline__ float fast_rcp(float x) {
#if __has_builtin(__builtin_amdgcn_rcpf)
  return __builtin_amdgcn_rcpf(x);
#else
  return 1.0f / x;
#endif
}

// Quantize one weight row (128 f32, optional sum of two rows, pre-scaled by gs)
// to single-i8 with per-column scale. Emits this lane's 2 B-fragments
// (k = half*64 + k0 + 0..15) and dequant constant kc = hscale*mx/(127*16256).
__device__ __forceinline__ void quant_row1(const float* __restrict__ ph,
                                           const float* __restrict__ pi,
                                           bool add_ih, float gs, float hscale,
                                           int k0, i32x4 wq[2], float& kc) {
  float mx = 1e-20f;
#pragma unroll
  for (int j = 0; j < 32; ++j) {
    float4v x = *(const float4v*)(ph + 4 * j);
    if (add_ih) x += *(const float4v*)(pi + 4 * j);
#pragma unroll
    for (int e = 0; e < 4; ++e) mx = fmaxf(mx, __builtin_fabsf(x[e]));
  }
  mx *= gs;
  const float inv = 127.0f * fast_rcp(mx);
#pragma unroll
  for (int half = 0; half < 2; ++half) {
    unsigned wd[4];
#pragma unroll
    for (int d = 0; d < 4; ++d) {
      unsigned accw = 0;
#pragma unroll
      for (int e = 0; e < 4; ++e) {
        const int k = half * 64 + k0 + d * 4 + e;
        float v = ph[k];
        if (add_ih) v += pi[k];
        float q = __builtin_rintf(v * gs * inv);
        q = fminf(fmaxf(q, -127.0f), 127.0f);
        accw |= ((unsigned)((int)q & 255)) << (8 * e);
      }
      wd[d] = accw;
    }
    wq[half] = (i32x4){(int)wd[0], (int)wd[1], (int)wd[2], (int)wd[3]};
  }
  kc = hscale * mx * (1.0f / (127.0f * 16256.0f));
}

// Two-limb i8 quantization of a row (for Wo): w ~= (mx/127)*(qh + ql/128).
__device__ __forceinline__ void quant_row2(const float* __restrict__ p, int k0,
                                           i32x4 qh[2], i32x4 ql[2], float& kc) {
  float mx = 1e-20f;
#pragma unroll
  for (int j = 0; j < 32; ++j) {
    float4v x = *(const float4v*)(p + 4 * j);
#pragma unroll
    for (int e = 0; e < 4; ++e) mx = fmaxf(mx, __builtin_fabsf(x[e]));
  }
  const float inv = 127.0f * fast_rcp(mx);
#pragma unroll
  for (int half = 0; half < 2; ++half) {
    unsigned wh[4], wl[4];
#pragma unroll
    for (int d = 0; d < 4; ++d) {
      unsigned ah = 0, al = 0;
#pragma unroll
      for (int e = 0; e < 4; ++e) {
        const int k = half * 64 + k0 + d * 4 + e;
        float u = p[k] * inv;
        float qhf = __builtin_rintf(u);
        qhf = fminf(fmaxf(qhf, -127.0f), 127.0f);
        float qlf = __builtin_rintf((u - qhf) * 128.0f);
        ah |= ((unsigned)((int)qhf & 255)) << (8 * e);
        al |= ((unsigned)((int)qlf & 255)) << (8 * e);
      }
      wh[d] = ah; wl[d] = al;
    }
    qh[half] = (i32x4){(int)wh[0], (int)wh[1], (int)wh[2], (int)wh[3]};
    ql[half] = (i32x4){(int)wl[0], (int)wl[1], (int)wl[2], (int)wl[3]};
  }
  kc = mx * (1.0f / (127.0f * 16256.0f));
}

__global__ __launch_bounds__(THREADS, 2) void lstm_decoder_kernel(
    const float* __restrict__ latent, const float* __restrict__ fc_w,
    const float* __restrict__ fc_b, const float* __restrict__ W_ih,
    const float* __restrict__ W_hh, const float* __restrict__ b_ih,
    const float* __restrict__ b_hh, const float* __restrict__ Wo,
    const float* __restrict__ bo, const int* __restrict__ seq_len_p,
    float* __restrict__ out) {
  const int tid = threadIdx.x;
  const int lane = tid & 63;
  const int w = tid >> 6;            // wave 0..7
  const int row0 = blockIdx.x * ROWS;
  const int T = seq_len_p[0];

  // Double-buffered i8 h tile: [16 rows][128 units]; row 2b=hi8, 2b+1=lo8.
  // phys byte = (row*128 + unit) ^ swzf(row).
  __shared__ __align__(16) signed char hbuf[2][16 * 128];

  // ---- h0 = latent @ fc_w^T + fc_b  -> buf 0 (scale S0 = 4) ----
  {
    const int u = tid & 127;
    const int rbase = tid >> 7;  // 0..3
#pragma unroll
    for (int pp = 0; pp < 2; ++pp) {
      const int bl = rbase + pp * 4;  // 0..7
      const float4v* lat4 = (const float4v*)(latent + (size_t)(row0 + bl) * L_DIM);
      const float4v* fw4  = (const float4v*)(fc_w + (size_t)u * L_DIM);
      float s = fc_b[u];
#pragma unroll
      for (int j = 0; j < L_DIM / 4; ++j) {
        float4v a = lat4[j], b = fw4[j];
        s += a[0] * b[0] + a[1] * b[1] + a[2] * b[2] + a[3] * b[3];
      }
      s = fminf(fmaxf(s, -3.99f), 3.99f);
      float qhf = __builtin_rintf(s * 31.75f);      // 127/4
      int hi8 = (int)qhf;
      float r = fmaf(qhf, -4.0f / 127.0f, s);
      int lo8 = (int)__builtin_rintf(r * 4064.0f);  // 16256/4
      const int mh = 2 * bl, ml = 2 * bl + 1;
      hbuf[0][(unsigned)(mh * 128 + u) ^ swzf(mh)] = (signed char)hi8;
      hbuf[0][(unsigned)(ml * 128 + u) ^ swzf(ml)] = (signed char)lo8;
    }
  }

  // ---- per-lane constants ----
  const int ub = (w << 4) + (lane & 15);   // this lane's hidden unit
  const int k0 = (lane >> 4) << 4;         // i8 K-offset (16 elems per group)
  const float gscb[4] = {LOG2E, LOG2E, 2.0f * LOG2E, LOG2E};
  float bias_y[4];
#pragma unroll
  for (int g = 0; g < 4; ++g)
    bias_y[g] = gscb[g] * (b_ih[g * 128 + ub] + b_hh[g * 128 + ub]);

  const int ocol = ((w & 3) << 4) + (lane & 15);
  const float bo_l = bo[ocol];

  // Wo fragments (i8 hi+lo limbs); used by waves 0-3
  i32x4 woh[2], wol[2];
  float kO;
  quant_row2(Wo + (size_t)ocol * H_DIM, k0, woh, wol, kO);

  // step-0 recurrent weights: W_hh only (x0 = 0); h0 scale 4 folded into kc
  i32x4 wfq[4][2];
  float kc[4];
#pragma unroll
  for (int g = 0; g < 4; ++g)
    quant_row1(W_hh + (size_t)(g * 128 + ub) * H_DIM,
               W_ih + (size_t)(g * 128 + ub) * H_DIM,
               /*add_ih=*/false, gscb[g], /*hscale=*/4.0f, k0, wfq[g], kc[g]);

  __syncthreads();  // h0 visible

  // ---- A-fragment offsets (row = lane&15, k = half*64 + k0 + 0..15) ----
  const int arow = lane & 15;
  const unsigned aoff0 = (unsigned)(arow * 128 + k0) ^ swzf(arow);
  const unsigned aoff1 = (unsigned)(arow * 128 + 64 + k0) ^ swzf(arow);
  i32x4 af[2];
  af[0] = *(const i32x4*)((const signed char*)hbuf[0] + aoff0);
  af[1] = *(const i32x4*)((const signed char*)hbuf[0] + aoff1);

  // write offsets: rows 4lg..4lg+3 = hiA, loA, hiB, loB at column ub
  const int lg = lane >> 4;
  unsigned woff[4];
#pragma unroll
  for (int r = 0; r < 4; ++r) {
    const int m = 4 * lg + r;
    woff[r] = (unsigned)(m * 128 + ub) ^ swzf(m);
  }

  float cA = 0.0f, cB = 0.0f;  // cell state for batch rows 2*lg, 2*lg+1
  float* pa = out + (size_t)(row0 + 2 * lg) * T * O_DIM + ocol;
  float* pb = out + (size_t)(row0 + 2 * lg + 1) * T * O_DIM + ocol;

  auto halfstep = [&](signed char* dst, bool reload) {
    // 1) gate MFMAs: i8 K=64, 2 instr per gate chain
    i32x4 acc[4];
#pragma unroll
    for (int g = 0; g < 4; ++g) {
      i32x4 a = {0, 0, 0, 0};
      a = __builtin_amdgcn_mfma_i32_16x16x64_i8(af[0], wfq[g][0], a, 0, 0, 0);
      a = __builtin_amdgcn_mfma_i32_16x16x64_i8(af[1], wfq[g][1], a, 0, 0, 0);
      acc[g] = a;
    }

    // 2) dequant: y = cvt(acc_e*128 + acc_o) * kc + bias  (*128 -> shift-add)
    float yv[8];
#pragma unroll
    for (int g = 0; g < 4; ++g) {
      const int giA = acc[g][0] * 128 + acc[g][1];
      const int giB = acc[g][2] * 128 + acc[g][3];
      yv[g]     = fmaf((float)giA, kc[g], bias_y[g]);
      yv[4 + g] = fmaf((float)giB, kc[g], bias_y[g]);
    }

    // 3) cell: paired rcp, fused sig(i)*tanh(g) and sig(o)*tanh(c); 13 trans
    float hA, hB;
    {
      float EfA = fast_exp2(-yv[1]), EfB = fast_exp2(-yv[5]);
      float DfA = 1.0f + EfA, DfB = 1.0f + EfB;
      float rf = fast_rcp(DfA * DfB);
      float sfA = rf * DfB, sfB = rf * DfA;

      float EiA = fast_exp2(-yv[0]), GA = fast_exp2(yv[2]);
      float EiB = fast_exp2(-yv[4]), GB = fast_exp2(yv[6]);
      float DgA = (1.0f + EiA) * (1.0f + GA);
      float DgB = (1.0f + EiB) * (1.0f + GB);
      float rg = fast_rcp(DgA * DgB);
      float sitA = (GA - 1.0f) * (rg * DgB);
      float sitB = (GB - 1.0f) * (rg * DgA);

      cA = fmaf(sfA, cA, sitA);
      cB = fmaf(sfB, cB, sitB);
      cA = fminf(fmaxf(cA, -15.0f), 15.0f);
      cB = fminf(fmaxf(cB, -15.0f), 15.0f);

      float CA = fast_exp2(2.0f * LOG2E * cA), EoA = fast_exp2(-yv[3]);
      float CB = fast_exp2(2.0f * LOG2E * cB), EoB = fast_exp2(-yv[7]);
      float PoA = (1.0f + EoA) * (1.0f + CA);
      float PoB = (1.0f + EoB) * (1.0f + CB);
      float rc = fast_rcp(PoA * PoB);
      hA = (CA - 1.0f) * (rc * PoB);
      hB = (CB - 1.0f) * (rc * PoA);
    }

    // 4) quantize h to 2 i8 limbs, write 4 bytes
    {
      float qhf = __builtin_rintf(hA * 127.0f);
      float r = fmaf(qhf, -1.0f / 127.0f, hA);
      dst[woff[0]] = (signed char)(int)qhf;
      dst[woff[1]] = (signed char)(int)__builtin_rintf(r * 16256.0f);
      qhf = __builtin_rintf(hB * 127.0f);
      r = fmaf(qhf, -1.0f / 127.0f, hB);
      dst[woff[2]] = (signed char)(int)qhf;
      dst[woff[3]] = (signed char)(int)__builtin_rintf(r * 16256.0f);
    }

    if (reload) {  // once, after step 0: combined (W_ih+W_hh), hscale=1
#pragma unroll
      for (int g = 0; g < 4; ++g)
        quant_row1(W_hh + (size_t)(g * 128 + ub) * H_DIM,
                   W_ih + (size_t)(g * 128 + ub) * H_DIM,
                   /*add_ih=*/true, gscb[g], /*hscale=*/1.0f, k0, wfq[g], kc[g]);
    }

    __syncthreads();  // h_{t+1} visible

    // 5) read new A fragments
    af[0] = *(const i32x4*)((const signed char*)dst + aoff0);
    af[1] = *(const i32x4*)((const signed char*)dst + aoff1);

    // 6) out_t = h_{t+1} @ Wo^T + bo  (waves 0-3), immediate store
    if (w < 4) {
      i32x4 p1 = {0, 0, 0, 0}, p2 = {0, 0, 0, 0};
      p1 = __builtin_amdgcn_mfma_i32_16x16x64_i8(af[0], woh[0], p1, 0, 0, 0);
      p1 = __builtin_amdgcn_mfma_i32_16x16x64_i8(af[1], woh[1], p1, 0, 0, 0);
      p2 = __builtin_amdgcn_mfma_i32_16x16x64_i8(af[0], wol[0], p2, 0, 0, 0);
      p2 = __builtin_amdgcn_mfma_i32_16x16x64_i8(af[1], wol[1], p2, 0, 0, 0);
      const int oiA = p1[0] * 128 + (p1[1] + p2[0] + (p2[1] >> 7));
      const int oiB = p1[2] * 128 + (p1[3] + p2[2] + (p2[3] >> 7));
      *pa = fmaf((float)oiA, kO, bo_l);
      *pb = fmaf((float)oiB, kO, bo_l);
    }
    pa += O_DIM;
    pb += O_DIM;
  };

#pragma unroll 1
  for (int tt = 0; tt < (T >> 1); ++tt) {
    halfstep(hbuf[1], tt == 0);
    halfstep(hbuf[0], false);
  }
  if (T & 1) halfstep(hbuf[1], T == 1);
}

extern "C" void kernel_launch(void* const* d_in, const int* in_sizes, int n_in,
                              void* d_out, int out_size, void* d_ws, size_t ws_size,
                              hipStream_t stream) {
  const float* latent = (const float*)d_in[0];
  const float* fc_w   = (const float*)d_in[1];
  const float* fc_b   = (const float*)d_in[2];
  const float* W_ih   = (const float*)d_in[3];
  const float* W_hh   = (const float*)d_in[4];
  const float* b_ih   = (const float*)d_in[5];
  const float* b_hh   = (const float*)d_in[6];
  const float* Wo     = (const float*)d_in[7];
  const float* bo     = (const float*)d_in[8];
  const int* seq_len  = (const int*)d_in[9];
  float* out = (float*)d_out;

  const int B = in_sizes[0] / L_DIM;  // 2048
  const int blocks = B / ROWS;        // 256 WGs -> 1 per CU

  hipLaunchKernelGGL(lstm_decoder_kernel, dim3(blocks), dim3(THREADS), 0, stream,
                     latent, fc_w, fc_b, W_ih, W_hh, b_ih, b_hh, Wo, bo, seq_len, out);
}

// Round 11
// 327.471 us; speedup vs baseline: 1.2428x; 1.2428x over previous
//
#include <hip/hip_runtime.h>
#include <hip/hip_bf16.h>

// LSTM decoder: B=2048, L=64, H=128, O=64, T=512.  Output: FLOAT32 [B,T,O].
// FINAL (r6 restored — best measured: 325 us, absmax 9.77e-4).
// Identities:
//   next input x == h  =>  t>=1: gates = h @ (W_ih+W_hh)^T + (b_ih+b_hh)
//   t==0 (x=0):            gates = h0 @ W_hh^T + (b_ih+b_hh)
// Precision: LDS h rows 2b=hi(h_b), 2b+1=lo(h_b); ONE MFMA pass vs W(bf16);
//   acc[even]+acc[odd] = (hi+lo)@W  (h full ~2^-17 precision through the
//   recurrence, W bf16-rounded once — fixed perturbation, damped by rho<1).
// Cell: shared-rcp form (13 trans/lane/step): paired rcps across the two
//   cells + fused sigma(i)*tanh(g); gate scales folded into W/b at load.
// Structure: 256 WGs (1/CU) x 8 waves; weights register-resident; h double-
//   buffered in swizzled LDS (1 barrier/step); c in fp32 regs.
// Structural floor (measured/modeled): step 1524 cyc = MFMA-pipe 700
//   (36 MFMA/SIMD @ 19.4cyc, M=16 forced by 8 batches/CU) + VALU 715
//   (13 trans + ~100 simple x 2 waves) + sync/LDS ~120-260. Serialized by the
//   recurrence; de-phasing refuted (r5 reorder +7, r8 2WG +86%, r9 prio null,
//   r7/r10 i8 net worse). Changing this needs packed-trans HW, K=64 bf16
//   MFMA, or B>=4096.

#define H_DIM 128
#define L_DIM 64
#define O_DIM 64
#define ROWS 8
#define THREADS 512
#define LOG2E 1.44269504f

typedef __attribute__((ext_vector_type(4))) float f32x4;
typedef __attribute__((ext_vector_type(4))) float float4v;
typedef __attribute__((ext_vector_type(8))) __bf16 bf16x8;
typedef __attribute__((ext_vector_type(8))) unsigned short u16x8;

__device__ __forceinline__ unsigned swzf(int r) {
  return (unsigned)(((r & 7) << 4) ^ ((r & 8) << 2));
}
__device__ __forceinline__ float fast_exp2(float x) {
#if __has_builtin(__builtin_amdgcn_exp2f)
  return __builtin_amdgcn_exp2f(x);
#else
  return exp2f(x);
#endif
}
__device__ __forceinline__ float fast_rcp(float x) {
#if __has_builtin(__builtin_amdgcn_rcpf)
  return __builtin_amdgcn_rcpf(x);
#else
  return 1.0f / x;
#endif
}
__device__ __forceinline__ unsigned short f2bf(float f) {
  unsigned u; __builtin_memcpy(&u, &f, 4);
  u = (u + 0x7FFFu + ((u >> 16) & 1u)) >> 16;
  return (unsigned short)u;
}
__device__ __forceinline__ void split2(float v, unsigned short& hi, unsigned short& lo) {
  __bf16 hb = (__bf16)v;
  __bf16 lb = (__bf16)(v - (float)hb);
  hi = __builtin_bit_cast(unsigned short, hb);
  lo = __builtin_bit_cast(unsigned short, lb);
}

// Recurrent-W fragments (bf16, gate scale folded: i,f,o x log2e; g x 2log2e).
__device__ __forceinline__ void load_wfrags(const float* __restrict__ W_ih,
                                            const float* __restrict__ W_hh,
                                            bool add_ih, int ub, int k0,
                                            bf16x8 wf[4][4]) {
  const float gsc[4] = {LOG2E, LOG2E, 2.0f * LOG2E, LOG2E};
#pragma unroll
  for (int g = 0; g < 4; ++g) {
    const float* ph = W_hh + (size_t)(g * 128 + ub) * H_DIM + k0;
    const float* pi = W_ih + (size_t)(g * 128 + ub) * H_DIM + k0;
    const float s = gsc[g];
#pragma unroll
    for (int kk = 0; kk < 4; ++kk) {
      float4v x0 = *(const float4v*)(ph + kk * 32);
      float4v x1 = *(const float4v*)(ph + kk * 32 + 4);
      if (add_ih) {
        x0 += *(const float4v*)(pi + kk * 32);
        x1 += *(const float4v*)(pi + kk * 32 + 4);
      }
      u16x8 b;
#pragma unroll
      for (int e = 0; e < 4; ++e) {
        b[e] = f2bf(s * x0[e]);
        b[e + 4] = f2bf(s * x1[e]);
      }
      wf[g][kk] = __builtin_bit_cast(bf16x8, b);
    }
  }
}

__global__ __launch_bounds__(THREADS, 2) void lstm_decoder_kernel(
    const float* __restrict__ latent, const float* __restrict__ fc_w,
    const float* __restrict__ fc_b, const float* __restrict__ W_ih,
    const float* __restrict__ W_hh, const float* __restrict__ b_ih,
    const float* __restrict__ b_hh, const float* __restrict__ Wo,
    const float* __restrict__ bo, const int* __restrict__ seq_len_p,
    float* __restrict__ out) {
  const int tid = threadIdx.x;
  const int lane = tid & 63;
  const int w = tid >> 6;            // wave 0..7
  const int row0 = blockIdx.x * ROWS;
  const int T = seq_len_p[0];

  // Double-buffered h tile: [16 rows][128 units] bf16; row 2b=hi, 2b+1=lo.
  // phys byte = (row*256 + col*2) ^ swzf(row).
  __shared__ __align__(16) unsigned short hbuf[2][16 * 128];

  // ---- h0 = latent @ fc_w^T + fc_b  -> buf 0 ----
  {
    const int u = tid & 127;
    const int rbase = tid >> 7;  // 0..3
#pragma unroll
    for (int pp = 0; pp < 2; ++pp) {
      const int bl = rbase + pp * 4;  // 0..7
      const float4v* lat4 = (const float4v*)(latent + (size_t)(row0 + bl) * L_DIM);
      const float4v* fw4  = (const float4v*)(fc_w + (size_t)u * L_DIM);
      float s = fc_b[u];
#pragma unroll
      for (int j = 0; j < L_DIM / 4; ++j) {
        float4v a = lat4[j], b = fw4[j];
        s += a[0] * b[0] + a[1] * b[1] + a[2] * b[2] + a[3] * b[3];
      }
      const int mh = 2 * bl, ml = 2 * bl + 1;
      unsigned short hh, ll;
      split2(s, hh, ll);
      *(unsigned short*)((char*)hbuf[0] + ((unsigned)(mh * 256 + u * 2) ^ swzf(mh))) = hh;
      *(unsigned short*)((char*)hbuf[0] + ((unsigned)(ml * 256 + u * 2) ^ swzf(ml))) = ll;
    }
  }

  // ---- per-lane constants ----
  const int ub = (w << 4) + (lane & 15);   // this lane's hidden unit
  const int k0 = (lane >> 4) << 3;
  const float gscb[4] = {LOG2E, LOG2E, 2.0f * LOG2E, LOG2E};
  float bias_g[4];
#pragma unroll
  for (int g = 0; g < 4; ++g)
    bias_g[g] = gscb[g] * (b_ih[g * 128 + ub] + b_hh[g * 128 + ub]);

  const int ocol = ((w & 3) << 4) + (lane & 15);
  const float bo_l = bo[ocol];

  // Wo fragments, single bf16 (A side carries hi+lo)
  bf16x8 wofrag[4];
#pragma unroll
  for (int kk = 0; kk < 4; ++kk) {
    const float* p = Wo + (size_t)ocol * H_DIM + k0 + kk * 32;
    float4v x0 = *(const float4v*)p;
    float4v x1 = *(const float4v*)(p + 4);
    u16x8 b;
#pragma unroll
    for (int e = 0; e < 4; ++e) { b[e] = f2bf(x0[e]); b[e + 4] = f2bf(x1[e]); }
    wofrag[kk] = __builtin_bit_cast(bf16x8, b);
  }

  // step-0 weights: W_hh only (x0 = 0)
  bf16x8 wf[4][4];
  load_wfrags(W_ih, W_hh, /*add_ih=*/false, ub, k0, wf);

  __syncthreads();  // h0 visible

  // ---- A-fragment read (row = lane&15, k = kk*32 + (lane>>4)*8 + e) ----
  bf16x8 af[4];
  const unsigned asw = swzf(lane & 15);
  const unsigned abase = (unsigned)((lane & 15) * 256 + ((lane >> 4) << 4));
#pragma unroll
  for (int kk = 0; kk < 4; ++kk)
    af[kk] = *(const bf16x8*)((const char*)hbuf[0] + ((abase + kk * 64) ^ asw));

  // write offsets: rows 4lg..4lg+3 = hiA, loA, hiB, loB at column ub
  const int lg = lane >> 4;
  unsigned woff[4];
#pragma unroll
  for (int r = 0; r < 4; ++r) {
    const int m = 4 * lg + r;
    woff[r] = (unsigned)((m * 256 + ub * 2) ^ swzf(m));
  }

  float cA = 0.0f, cB = 0.0f;  // cell state for batch rows 2*lg, 2*lg+1
  float* pa = out + (size_t)(row0 + 2 * lg) * T * O_DIM + ocol;
  float* pb = out + (size_t)(row0 + 2 * lg + 1) * T * O_DIM + ocol;

  auto halfstep = [&](unsigned short* dst, bool reload) {
    // 1) gate MFMAs
    f32x4 acc[4];
#pragma unroll
    for (int g = 0; g < 4; ++g) {
      f32x4 a = {bias_g[g], 0.0f, bias_g[g], 0.0f};
#pragma unroll
      for (int kk = 0; kk < 4; ++kk)
        a = __builtin_amdgcn_mfma_f32_16x16x32_bf16(af[kk], wf[g][kk], a, 0, 0, 0);
      acc[g] = a;
    }

    // 2) element-wise cell, shared-rcp form (13 trans/lane/step)
    float hA, hB;
    {
      float yiA = acc[0][0] + acc[0][1], yfA = acc[1][0] + acc[1][1];
      float ygA = acc[2][0] + acc[2][1], yoA = acc[3][0] + acc[3][1];
      float yiB = acc[0][2] + acc[0][3], yfB = acc[1][2] + acc[1][3];
      float ygB = acc[2][2] + acc[2][3], yoB = acc[3][2] + acc[3][3];

      float EiA = fast_exp2(-yiA), EfA = fast_exp2(-yfA);
      float GgA = fast_exp2(ygA),  EoA = fast_exp2(-yoA);
      float EiB = fast_exp2(-yiB), EfB = fast_exp2(-yfB);
      float GgB = fast_exp2(ygB),  EoB = fast_exp2(-yoB);

      float DfA = 1.0f + EfA, DfB = 1.0f + EfB;
      float rf = fast_rcp(DfA * DfB);
      float sfA = rf * DfB, sfB = rf * DfA;

      float DiGA = (1.0f + EiA) * (1.0f + GgA);
      float DiGB = (1.0f + EiB) * (1.0f + GgB);
      float rg = fast_rcp(DiGA * DiGB);
      float sitA = (GgA - 1.0f) * (rg * DiGB);
      float sitB = (GgB - 1.0f) * (rg * DiGA);

      cA = fmaf(sfA, cA, sitA);
      cB = fmaf(sfB, cB, sitB);

      float tcA = 1.0f - 2.0f * fast_rcp(1.0f + fast_exp2(2.0f * LOG2E * cA));
      float tcB = 1.0f - 2.0f * fast_rcp(1.0f + fast_exp2(2.0f * LOG2E * cB));

      float DoA = 1.0f + EoA, DoB = 1.0f + EoB;
      float ro = fast_rcp(DoA * DoB);
      hA = (ro * DoB) * tcA;
      hB = (ro * DoA) * tcB;
    }

    // 3) write h_{k+1} split into the other buffer
    {
      unsigned short hh, ll;
      split2(hA, hh, ll);
      *(unsigned short*)((char*)dst + woff[0]) = hh;
      *(unsigned short*)((char*)dst + woff[1]) = ll;
      split2(hB, hh, ll);
      *(unsigned short*)((char*)dst + woff[2]) = hh;
      *(unsigned short*)((char*)dst + woff[3]) = ll;
    }

    if (reload)  // once, after step 0: switch to combined (W_ih+W_hh)
      load_wfrags(W_ih, W_hh, /*add_ih=*/true, ub, k0, wf);

    __syncthreads();  // h_{k+1} visible

    // 4) read h_{k+1} fragments
#pragma unroll
    for (int kk = 0; kk < 4; ++kk)
      af[kk] = *(const bf16x8*)((const char*)dst + ((abase + kk * 64) ^ asw));

    // 5) out_t = h_{k+1} @ Wo^T + bo  (waves 0-3), immediate store
    if (w < 4) {
      f32x4 ao = {bo_l, 0.0f, bo_l, 0.0f};
#pragma unroll
      for (int kk = 0; kk < 4; ++kk)
        ao = __builtin_amdgcn_mfma_f32_16x16x32_bf16(af[kk], wofrag[kk], ao, 0, 0, 0);
      *pa = ao[0] + ao[1];
      *pb = ao[2] + ao[3];
    }
    pa += O_DIM;
    pb += O_DIM;
  };

#pragma unroll 1
  for (int tt = 0; tt < (T >> 1); ++tt) {
    halfstep(hbuf[1], tt == 0);
    halfstep(hbuf[0], false);
  }
  if (T & 1) halfstep(hbuf[1], T == 1);
}

extern "C" void kernel_launch(void* const* d_in, const int* in_sizes, int n_in,
                              void* d_out, int out_size, void* d_ws, size_t ws_size,
                              hipStream_t stream) {
  const float* latent = (const float*)d_in[0];
  const float* fc_w   = (const float*)d_in[1];
  const float* fc_b   = (const float*)d_in[2];
  const float* W_ih   = (const float*)d_in[3];
  const float* W_hh   = (const float*)d_in[4];
  const float* b_ih   = (const float*)d_in[5];
  const float* b_hh   = (const float*)d_in[6];
  const float* Wo     = (const float*)d_in[7];
  const float* bo     = (const float*)d_in[8];
  const int* seq_len  = (const int*)d_in[9];
  float* out = (float*)d_out;

  const int B = in_sizes[0] / L_DIM;  // 2048
  const int blocks = B / ROWS;        // 256 WGs -> 1 per CU

  hipLaunchKernelGGL(lstm_decoder_kernel, dim3(blocks), dim3(THREADS), 0, stream,
                     latent, fc_w, fc_b, W_ih, W_hh, b_ih, b_hh, Wo, bo, seq_len, out);
}